// Round 10
// baseline (505.175 us; speedup 1.0000x reference)
//
#include <hip/hip_runtime.h>
#include <math.h>
#include <float.h>

// Problem constants (HierNet_55705725829422)
#define NN 50000      // nodes
#define EE 800000     // edges
#define CAP 64        // max in-degree capacity (Poisson(16): P(>=64) ~ 1e-19)

typedef unsigned short ushort_t;
typedef short short8 __attribute__((ext_vector_type(8)));
typedef float floatx4 __attribute__((ext_vector_type(4)));
typedef float vfloat4 __attribute__((ext_vector_type(4)));  // native vec for nontemporal builtins

__device__ __constant__ float kAVG_LOG = 2.8332133440562162f; // log(17)

__device__ inline ushort_t f2bf(float v) {
    union { float f; unsigned u; } x; x.f = v;
    unsigned r = x.u + 0x7fffu + ((x.u >> 16) & 1u);
    return (ushort_t)(r >> 16);
}
__device__ inline float bf2f(ushort_t b) {
    union { unsigned u; float f; } x; x.u = ((unsigned)b) << 16; return x.f;
}
__device__ inline float bitsf(unsigned u) {
    union { unsigned u; float f; } x; x.u = u; return x.f;
}
__device__ inline void splitbf(float v, ushort_t& hi, ushort_t& lo) {
    hi = f2bf(v);
    lo = f2bf(v - bf2f(hi));
}

// merged init: zero cnt+pool, cast x -> bf16
__global__ __launch_bounds__(256) void init_kernel(int* cnt, float* pool, const float* __restrict__ x,
                                                   ushort_t* __restrict__ xb) {
    int i = blockIdx.x * 256 + threadIdx.x;
    if (i < NN * 32) xb[i] = f2bf(x[i]);
    if (i < NN) cnt[i] = 0;
    if (i < 64 * 64) pool[i] = 0.f;
}

// CSR build: packed 16B entries {src_bits, ea.x, ea.y, pad}, 4 edges/thread, nt stores
__global__ __launch_bounds__(256) void build_csr(const int* __restrict__ ei, const float* __restrict__ ea,
                                                 int* __restrict__ cnt, float4* __restrict__ csr) {
    int e0 = (blockIdx.x * 256 + threadIdx.x) * 4;
    if (e0 >= EE) return;
    int4 s4 = *(const int4*)(ei + e0);
    int4 d4 = *(const int4*)(ei + EE + e0);
    float4 eaA = *(const float4*)(ea + 2 * e0);      // e0, e0+1
    float4 eaB = *(const float4*)(ea + 2 * e0 + 4);  // e0+2, e0+3
    int p0 = atomicAdd(&cnt[d4.x], 1);
    int p1 = atomicAdd(&cnt[d4.y], 1);
    int p2 = atomicAdd(&cnt[d4.z], 1);
    int p3 = atomicAdd(&cnt[d4.w], 1);
    if (p0 < CAP) {
        vfloat4 v = {bitsf((unsigned)s4.x), eaA.x, eaA.y, 0.f};
        __builtin_nontemporal_store(v, (vfloat4*)&csr[d4.x * CAP + p0]);
    }
    if (p1 < CAP) {
        vfloat4 v = {bitsf((unsigned)s4.y), eaA.z, eaA.w, 0.f};
        __builtin_nontemporal_store(v, (vfloat4*)&csr[d4.y * CAP + p1]);
    }
    if (p2 < CAP) {
        vfloat4 v = {bitsf((unsigned)s4.z), eaB.x, eaB.y, 0.f};
        __builtin_nontemporal_store(v, (vfloat4*)&csr[d4.z * CAP + p2]);
    }
    if (p3 < CAP) {
        vfloat4 v = {bitsf((unsigned)s4.w), eaB.z, eaB.w, 0.f};
        __builtin_nontemporal_store(v, (vfloat4*)&csr[d4.w * CAP + p3]);
    }
}

// per-layer A/B-projection weight prep: U, Wab (fp32), bias_ab
template <int F>
__global__ __launch_bounds__(256) void prep_ab(const float* __restrict__ We, const float* __restrict__ be,
                                               const float* __restrict__ Wpre, const float* __restrict__ bpre,
                                               float* __restrict__ U, float* __restrict__ Wab,
                                               float* __restrict__ bias_ab) {
    const int TF = 2 * F;
    int tid = threadIdx.x;
    for (int idx = tid; idx < 2 * TF; idx += 256) {
        int c = idx / TF, f = idx % TF;
        int t = f / F, o = f % F;
        float s = 0.f;
        for (int g = 0; g < F; ++g)
            s += We[c * F + g] * Wpre[((size_t)t * 3 * F + 2 * F + g) * F + o];
        U[idx] = s;
    }
    for (int idx = tid; idx < F * 2 * TF; idx += 256) {
        int g = idx / (2 * TF), cc = idx % (2 * TF);
        int t, o, row;
        if (cc < TF) { t = cc / F; o = cc % F; row = g; }
        else { int c2 = cc - TF; t = c2 / F; o = c2 % F; row = F + g; }
        Wab[idx] = Wpre[((size_t)t * 3 * F + row) * F + o];
    }
    for (int cc = tid; cc < 2 * TF; cc += 256) {
        float v = 0.f;
        if (cc < TF) {
            int t = cc / F, o = cc % F;
            float s = 0.f;
            for (int g = 0; g < F; ++g)
                s += be[g] * Wpre[((size_t)t * 3 * F + 2 * F + g) * F + o];
            v = s + bpre[t * F + o];
        }
        bias_ab[cc] = v;
    }
}

// Folded Z/final weights, split to bf16 hi/lo, stored COL-MAJOR [192 cols][KT]
template <int F>
__global__ __launch_bounds__(256) void prep_zf(const float* __restrict__ Wpost, const float* __restrict__ Wlin,
                                               const float* __restrict__ bpost, const float* __restrict__ blin,
                                               ushort_t* __restrict__ Bh, ushort_t* __restrict__ Bl,
                                               float* __restrict__ bias_zf) {
    const int KT = 9 * F;
    int bx = blockIdx.x;  // 12 blocks x 16 cols
    int tid = threadIdx.x;
    for (int idx = tid; idx < 16 * KT; idx += 256) {
        int jj = idx / KT, k = idx % KT;
        int jg = bx * 16 + jj;
        int b = jg >> 6, j = jg & 63;
        float v = 0.f;
        if (k < F) {
            if (b == 0) {
                float s = 0.f;
                for (int t = 0; t < 2; ++t)
                    for (int c = 0; c < 32; ++c)
                        s += Wpost[((size_t)t * 13 * F + k) * 32 + c] * Wlin[(t * 32 + c) * 64 + j];
                v = s;
            }
        } else {
            int r = k - F;
            int t = r / (4 * F), rr = r - t * 4 * F;
            float s = 0.f;
            for (int c = 0; c < 32; ++c)
                s += Wpost[((size_t)t * 13 * F + F + b * 4 * F + rr) * 32 + c] * Wlin[(t * 32 + c) * 64 + j];
            v = s;
        }
        ushort_t h_, l_;
        splitbf(v, h_, l_);
        Bh[(size_t)jg * KT + k] = h_;
        Bl[(size_t)jg * KT + k] = l_;
    }
    if (bx == 0) {
        for (int j = tid; j < 64; j += 256) {
            float s = blin[j];
            for (int t = 0; t < 2; ++t)
                for (int c = 0; c < 32; ++c)
                    s += bpost[t * 32 + c] * Wlin[(t * 32 + c) * 64 + j];
            bias_zf[j] = s;
        }
    }
}

// fp32 GEMM: [Ca | Cb] = A[MxK]@B[KxN] + bias. Columns < bstart -> fp32 Ca; >= bstart -> bf16 Cb.
__global__ __launch_bounds__(256) void gemm_bias(const float* __restrict__ A, const float* __restrict__ B,
                                                 const float* __restrict__ bias, float* __restrict__ Ca,
                                                 ushort_t* __restrict__ Cb, int M, int K, int Ncols, int bstart) {
    __shared__ float As[32][132];
    __shared__ float Bs[32][68];
    int m0 = blockIdx.x * 128, c0 = blockIdx.y * 64;
    int tid = threadIdx.x;
    int tx = tid & 15, ty = tid >> 4;
    int ms = tid >> 3, u = tid & 7;
    float acc[8][4] = {};
    for (int k0 = 0; k0 < K; k0 += 32) {
#pragma unroll
        for (int p = 0; p < 4; ++p) {
            int m = ms + 32 * p;
            int gm = m0 + m;
            float4 v = make_float4(0.f, 0.f, 0.f, 0.f);
            if (gm < M) v = *(const float4*)(A + (size_t)gm * K + k0 + u * 4);
            As[u * 4 + 0][m] = v.x; As[u * 4 + 1][m] = v.y;
            As[u * 4 + 2][m] = v.z; As[u * 4 + 3][m] = v.w;
        }
#pragma unroll
        for (int p = 0; p < 2; ++p) {
            int idx = tid + 256 * p;
            int kk = idx >> 4, q = idx & 15;
            *(float4*)&Bs[kk][q * 4] = *(const float4*)(B + (size_t)(k0 + kk) * Ncols + c0 + q * 4);
        }
        __syncthreads();
#pragma unroll 8
        for (int k = 0; k < 32; ++k) {
            float a0[8], b0[4];
            *(float4*)&a0[0] = *(const float4*)&As[k][ty * 8];
            *(float4*)&a0[4] = *(const float4*)&As[k][ty * 8 + 4];
            *(float4*)&b0[0] = *(const float4*)&Bs[k][tx * 4];
#pragma unroll
            for (int i = 0; i < 8; ++i)
#pragma unroll
                for (int j = 0; j < 4; ++j) acc[i][j] = fmaf(a0[i], b0[j], acc[i][j]);
        }
        __syncthreads();
    }
    float bj[4];
#pragma unroll
    for (int j = 0; j < 4; ++j) bj[j] = bias[c0 + tx * 4 + j];
    bool bside = (c0 >= bstart);
    int TFw = bstart;  // row stride of both halves
#pragma unroll
    for (int i = 0; i < 8; ++i) {
        int gm = m0 + ty * 8 + i;
        if (gm >= M) continue;
        float v0 = acc[i][0] + bj[0], v1 = acc[i][1] + bj[1];
        float v2 = acc[i][2] + bj[2], v3 = acc[i][3] + bj[3];
        if (!bside) {
            *(float4*)(Ca + (size_t)gm * TFw + c0 + tx * 4) = make_float4(v0, v1, v2, v3);
        } else {
            ushort4 w;
            w.x = f2bf(v0); w.y = f2bf(v1); w.z = f2bf(v2); w.w = f2bf(v3);
            *(ushort4*)(Cb + (size_t)gm * TFw + (c0 - bstart) + tx * 4) = w;
        }
    }
}

// aggregate: ONE wave per node, packed 16B CSR entries, bf16 gather. Emits agg as plain bf16.
template <int F>
__global__ __launch_bounds__(256) void aggregate(const float* __restrict__ ABa, const ushort_t* __restrict__ ABb,
                                                 const int* __restrict__ cnt, const float4* __restrict__ csr,
                                                 const float* __restrict__ U,
                                                 ushort_t* __restrict__ agg_b, float2* __restrict__ sc) {
    const int TF = 2 * F;
    const int FPL = TF / 64;  // 1 (F=32) or 2 (F=64)
    int lane = threadIdx.x & 63;
    int n = blockIdx.x * 4 + (threadIdx.x >> 6);
    if (n >= NN) return;
    int f0 = FPL * lane;

    float base[FPL], u0[FPL], u1[FPL], sum[FPL], sq[FPL], mn[FPL], mx[FPL];
#pragma unroll
    for (int r = 0; r < FPL; ++r) {
        base[r] = ABa[(size_t)n * TF + f0 + r];
        u0[r] = U[f0 + r];
        u1[r] = U[TF + f0 + r];
        sum[r] = 0.f; sq[r] = 0.f; mn[r] = FLT_MAX; mx[r] = -FLT_MAX;
    }
    int deg = cnt[n];
    int ec = deg < CAP ? deg : CAP;
    if (ec > 0) {
        int ebase = n * CAP;
        int myi = lane < ec ? lane : ec - 1;
        float4 ent = csr[ebase + myi];
        int msrc = __float_as_int(ent.x);
        float meax = ent.y, meay = ent.z;
        for (int e = 0; e < ec; e += 8) {
            int sb[8]; float ex[8], ey[8];
            unsigned wv[8];
#pragma unroll
            for (int i = 0; i < 8; ++i) {
                sb[i] = __shfl(msrc, e + i);
                ex[i] = __shfl(meax, e + i);
                ey[i] = __shfl(meay, e + i);
            }
#pragma unroll
            for (int i = 0; i < 8; ++i) {
                if (e + i < ec) {
                    if constexpr (FPL == 2)
                        wv[i] = *(const unsigned*)(ABb + (size_t)sb[i] * TF + f0);
                    else
                        wv[i] = ABb[(size_t)sb[i] * TF + f0];
                }
            }
#pragma unroll
            for (int i = 0; i < 8; ++i) {
                if (e + i < ec) {
                    float v[FPL];
                    if constexpr (FPL == 2) {
                        v[0] = bitsf(wv[i] << 16);
                        v[1] = bitsf(wv[i] & 0xffff0000u);
                    } else {
                        v[0] = bitsf(wv[i] << 16);
                    }
#pragma unroll
                    for (int r = 0; r < FPL; ++r) {
                        float q = fmaf(ex[i], u0[r], fmaf(ey[i], u1[r], v[r]));
                        sum[r] += q;
                        sq[r] = fmaf(q, q, sq[r]);
                        mn[r] = fminf(mn[r], q);
                        mx[r] = fmaxf(mx[r], q);
                    }
                }
            }
        }
    }
    float d = (float)(deg > 1 ? deg : 1);
    float inv_d = 1.f / d;
    bool has = deg > 0;
#pragma unroll
    for (int r = 0; r < FPL; ++r) {
        float mean_q = sum[r] * inv_d;
        float var = sq[r] * inv_d - mean_q * mean_q;
        float stdv = sqrtf(fmaxf(var, 0.f) + 1e-5f);
        float mean = has ? base[r] + mean_q : 0.f;
        float vmn = has ? base[r] + mn[r] : 0.f;
        float vmx = has ? base[r] + mx[r] : 0.f;
        int f = f0 + r;
        int t = f / F, o = f - t * F;
        size_t rowb = (size_t)n * (4 * TF) + (size_t)t * (4 * F);
        agg_b[rowb + o] = f2bf(mean);
        agg_b[rowb + F + o] = f2bf(vmn);
        agg_b[rowb + 2 * F + o] = f2bf(vmx);
        agg_b[rowb + 3 * F + o] = f2bf(stdv);
    }
    if (lane == 0) {
        float logd = logf(d + 1.f);
        sc[n] = make_float2(logd / kAVG_LOG, kAVG_LOG / logd);
    }
}

// MFMA merged Z+final GEMM. A bf16 (single), B split hi/lo: Y = Ah@Bh + Ah@Bl.
// Block 64 rows x 192 cols; wave w owns col-frags {w, w+4, w+8} x 4 row-frags.
// Register-prefetch pipeline: k0+1 global loads issued before k0's MFMA block.
template <int F, bool POOL>
__global__ __launch_bounds__(256) void gemm_zf(
    const ushort_t* __restrict__ xs_b, const ushort_t* __restrict__ agg_b,
    const ushort_t* __restrict__ Bh, const ushort_t* __restrict__ Bl,
    const float* __restrict__ bias_zf, const float2* __restrict__ sc,
    float* __restrict__ H, ushort_t* __restrict__ H_b,
    const int* __restrict__ batch, float* __restrict__ pool) {
    const int KT = 9 * F;
    extern __shared__ char smem[];
    ushort_t* A_s  = (ushort_t*)smem;        // [64][40]
    ushort_t* Bh_s = A_s + 64 * 40;          // [192][40]
    ushort_t* Bl_s = Bh_s + 192 * 40;        // [192][40]
    float* hbuf = (float*)smem;              // POOL alias [64][68]

    int m0 = blockIdx.x * 64;
    int tid = threadIdx.x;
    int lane = tid & 63;
    int wave = tid >> 6;
    int ln = lane & 15, quad = lane >> 4;

    floatx4 acc[4][3];
#pragma unroll
    for (int i = 0; i < 4; ++i)
#pragma unroll
        for (int j = 0; j < 3; ++j) acc[i][j] = (floatx4)(0.f);

    int arow = tid >> 2, asg = tid & 3;
    int agm = m0 + arow;
    int bcol[3], bsg[3];
#pragma unroll
    for (int p = 0; p < 3; ++p) {
        int idx = tid + 256 * p;
        bcol[p] = idx >> 2;
        bsg[p] = idx & 3;
    }

    const short8 zero8 = {0, 0, 0, 0, 0, 0, 0, 0};
    short8 pa, pbh[3], pbl[3];
    // prefetch k0 = 0
    {
        int c0 = asg * 8;  // always < F at k0=0
        pa = zero8;
        if (agm < NN) pa = *(const short8*)(xs_b + (size_t)agm * F + c0);
#pragma unroll
        for (int p = 0; p < 3; ++p) {
            pbh[p] = *(const short8*)(Bh + (size_t)bcol[p] * KT + bsg[p] * 8);
            pbl[p] = *(const short8*)(Bl + (size_t)bcol[p] * KT + bsg[p] * 8);
        }
    }

    for (int k0 = 0; k0 < KT; k0 += 32) {
        // write staged regs -> LDS
        *(short8*)&A_s[arow * 40 + asg * 8] = pa;
#pragma unroll
        for (int p = 0; p < 3; ++p) {
            *(short8*)&Bh_s[bcol[p] * 40 + bsg[p] * 8] = pbh[p];
            *(short8*)&Bl_s[bcol[p] * 40 + bsg[p] * 8] = pbl[p];
        }
        __syncthreads();
        short8 ah[4], bh[3], bl[3];
#pragma unroll
        for (int rf = 0; rf < 4; ++rf)
            ah[rf] = *(short8*)&A_s[(rf * 16 + ln) * 40 + quad * 8];
#pragma unroll
        for (int b = 0; b < 3; ++b) {
            int col = b * 64 + wave * 16 + ln;
            bh[b] = *(short8*)&Bh_s[col * 40 + quad * 8];
            bl[b] = *(short8*)&Bl_s[col * 40 + quad * 8];
        }
        // issue next-k0 global loads (overlap with MFMA below)
        int kn = k0 + 32;
        if (kn < KT) {
            int c0 = kn + asg * 8;
            pa = zero8;
            if (agm < NN) {
                pa = (c0 < F) ? *(const short8*)(xs_b + (size_t)agm * F + c0)
                              : *(const short8*)(agg_b + (size_t)agm * 8 * F + (c0 - F));
            }
#pragma unroll
            for (int p = 0; p < 3; ++p) {
                pbh[p] = *(const short8*)(Bh + (size_t)bcol[p] * KT + kn + bsg[p] * 8);
                pbl[p] = *(const short8*)(Bl + (size_t)bcol[p] * KT + kn + bsg[p] * 8);
            }
        }
#pragma unroll
        for (int rf = 0; rf < 4; ++rf)
#pragma unroll
            for (int b = 0; b < 3; ++b) {
                acc[rf][b] = __builtin_amdgcn_mfma_f32_16x16x32_bf16(ah[rf], bh[b], acc[rf][b], 0, 0, 0);
                acc[rf][b] = __builtin_amdgcn_mfma_f32_16x16x32_bf16(ah[rf], bl[b], acc[rf][b], 0, 0, 0);
            }
        __syncthreads();
    }

    int ocol = wave * 16 + ln;  // output col 0..63
    float bcolv = bias_zf[ocol];

#pragma unroll
    for (int rf = 0; rf < 4; ++rf) {
#pragma unroll
        for (int reg = 0; reg < 4; ++reg) {
            int r = rf * 16 + quad * 4 + reg;
            int gm = m0 + r;
            float2 s = make_float2(0.f, 0.f);
            if (gm < NN) s = sc[gm];
            float y = acc[rf][0][reg] + s.x * acc[rf][1][reg] + s.y * acc[rf][2][reg] + bcolv;
            y = fmaxf(y, 0.f);
            if (POOL) {
                hbuf[r * 68 + ocol] = (gm < NN) ? y : 0.f;
            } else if (gm < NN) {
                H[(size_t)gm * 64 + ocol] = y;
                H_b[(size_t)gm * 64 + ocol] = f2bf(y);
            }
        }
    }
    if (POOL) {
        __syncthreads();
        int col = tid & 63, grp = tid >> 6;
        float a = 0.f;
        int cur = -1;
        for (int i = 0; i < 16; ++i) {
            int r = grp * 16 + i;
            int gm = m0 + r;
            if (gm >= NN) break;
            int b = batch[gm];
            if (b != cur) {
                if (cur >= 0) atomicAdd(&pool[cur * 64 + col], a);
                cur = b; a = 0.f;
            }
            a += hbuf[r * 68 + col];
        }
        if (cur >= 0) atomicAdd(&pool[cur * 64 + col], a);
    }
}

__global__ __launch_bounds__(256) void head_kernel(const float* __restrict__ gpool, const float* __restrict__ hls,
                                                   const float* __restrict__ W1, const float* __restrict__ b1,
                                                   const float* __restrict__ W2, const float* __restrict__ b2,
                                                   const float* __restrict__ W3, const float* __restrict__ b3,
                                                   float* __restrict__ out) {
    __shared__ float gin[64][96];
    __shared__ float r1[64][64];
    __shared__ float r2[64][64];
    int tid = threadIdx.x;
    for (int idx = tid; idx < 64 * 96; idx += 256) {
        int g = idx / 96, j = idx % 96;
        gin[g][j] = (j < 64) ? gpool[g * 64 + j] : hls[g * 32 + (j - 64)];
    }
    __syncthreads();
    for (int idx = tid; idx < 64 * 64; idx += 256) {
        int g = idx / 64, j = idx % 64;
        float acc = b1[j];
        for (int k = 0; k < 96; ++k) acc = fmaf(gin[g][k], W1[k * 64 + j], acc);
        r1[g][j] = fmaxf(acc, 0.f);
    }
    __syncthreads();
    for (int idx = tid; idx < 64 * 64; idx += 256) {
        int g = idx / 64, j = idx % 64;
        float acc = b2[j];
        for (int k = 0; k < 64; ++k) acc = fmaf(r1[g][k], W2[k * 64 + j], acc);
        r2[g][j] = fmaxf(acc, 0.f);
    }
    __syncthreads();
    if (tid < 64) {
        float acc = b3[0];
        for (int k = 0; k < 64; ++k) acc = fmaf(r2[tid][k], W3[k], acc);
        out[tid] = acc;
    }
}

extern "C" void kernel_launch(void* const* d_in, const int* in_sizes, int n_in,
                              void* d_out, int out_size, void* d_ws, size_t ws_size,
                              hipStream_t stream) {
    (void)in_sizes; (void)n_in; (void)out_size; (void)ws_size;
    const float* x     = (const float*)d_in[0];
    const float* eattr = (const float*)d_in[1];
    const float* hls   = (const float*)d_in[2];
    const int*   eidx  = (const int*)d_in[3];
    const int*   batch = (const int*)d_in[4];
    const float* We[2]    = {(const float*)d_in[5],  (const float*)d_in[13]};
    const float* be[2]    = {(const float*)d_in[6],  (const float*)d_in[14]};
    const float* Wpre[2]  = {(const float*)d_in[7],  (const float*)d_in[15]};
    const float* bpre[2]  = {(const float*)d_in[8],  (const float*)d_in[16]};
    const float* Wpost[2] = {(const float*)d_in[9],  (const float*)d_in[17]};
    const float* bpost[2] = {(const float*)d_in[10], (const float*)d_in[18]};
    const float* Wlin[2]  = {(const float*)d_in[11], (const float*)d_in[19]};
    const float* blin[2]  = {(const float*)d_in[12], (const float*)d_in[20]};
    const float* W1 = (const float*)d_in[21]; const float* b1 = (const float*)d_in[22];
    const float* W2 = (const float*)d_in[23]; const float* b2 = (const float*)d_in[24];
    const float* W3 = (const float*)d_in[25]; const float* b3 = (const float*)d_in[26];
    float* out = (float*)d_out;

    char* ws = (char*)d_ws;
    size_t off = 0;
    auto carve = [&](size_t bytes) -> char* {
        char* p = ws + off;
        off = (off + bytes + 255) & ~(size_t)255;
        return p;
    };
    int*      cnt     = (int*)carve((size_t)NN * 4);
    float4*   csr     = (float4*)carve((size_t)NN * CAP * 16);
    float*    ABa     = (float*)carve((size_t)NN * 128 * 4);      // fp32 dst-projection
    ushort_t* ABb     = (ushort_t*)carve((size_t)NN * 128 * 2);   // bf16 src-projection
    ushort_t* agg_b   = (ushort_t*)carve((size_t)NN * 512 * 2);   // bf16 agg
    float2*   sc      = (float2*)carve((size_t)NN * 8);
    ushort_t* xs_b    = (ushort_t*)carve((size_t)NN * 32 * 2);
    float*    h1      = (float*)carve((size_t)NN * 64 * 4);
    ushort_t* h1_b    = (ushort_t*)carve((size_t)NN * 64 * 2);
    float*    U       = (float*)carve(256 * 4);
    float*    Wab     = (float*)carve(16384 * 4);
    float*    bias_ab = (float*)carve(256 * 4);
    ushort_t* Bh      = (ushort_t*)carve((size_t)192 * 576 * 2);
    ushort_t* Bl      = (ushort_t*)carve((size_t)192 * 576 * 2);
    float*    bias_zf = (float*)carve(64 * 4);
    float*    pool    = (float*)carve(64 * 64 * 4);

    const int MB128 = (NN + 127) / 128;  // 391
    const int MB64  = (NN + 63) / 64;    // 782
    const int SMEM_ZF = (64 * 40 + 192 * 40 + 192 * 40) * 2;  // 35840

    init_kernel<<<(NN * 32 + 255) / 256, 256, 0, stream>>>(cnt, pool, x, xs_b);
    build_csr<<<(EE / 4 + 255) / 256, 256, 0, stream>>>(eidx, eattr, cnt, csr);

    // ---------------- layer 0 (F=32, TF=64, KT=288) ----------------
    prep_ab<32><<<1, 256, 0, stream>>>(We[0], be[0], Wpre[0], bpre[0], U, Wab, bias_ab);
    prep_zf<32><<<12, 256, 0, stream>>>(Wpost[0], Wlin[0], bpost[0], blin[0], Bh, Bl, bias_zf);
    gemm_bias<<<dim3(MB128, 2), 256, 0, stream>>>(x, Wab, bias_ab, ABa, ABb, NN, 32, 128, 64);
    aggregate<32><<<(NN + 3) / 4, 256, 0, stream>>>(ABa, ABb, cnt, csr, U, agg_b, sc);
    gemm_zf<32, false><<<MB64, 256, SMEM_ZF, stream>>>(xs_b, agg_b, Bh, Bl, bias_zf, sc,
                                                       h1, h1_b, batch, pool);

    // ---------------- layer 1 (F=64, TF=128, KT=576) ----------------
    prep_ab<64><<<1, 256, 0, stream>>>(We[1], be[1], Wpre[1], bpre[1], U, Wab, bias_ab);
    prep_zf<64><<<12, 256, 0, stream>>>(Wpost[1], Wlin[1], bpost[1], blin[1], Bh, Bl, bias_zf);
    gemm_bias<<<dim3(MB128, 4), 256, 0, stream>>>(h1, Wab, bias_ab, ABa, ABb, NN, 64, 256, 128);
    aggregate<64><<<(NN + 3) / 4, 256, 0, stream>>>(ABa, ABb, cnt, csr, U, agg_b, sc);
    gemm_zf<64, true><<<MB64, 256, SMEM_ZF, stream>>>(h1_b, agg_b, Bh, Bl, bias_zf, sc,
                                                      nullptr, nullptr, batch, pool);

    // ---------------- head ----------------
    head_kernel<<<1, 256, 0, stream>>>(pool, hls, W1, b1, W2, b2, W3, b3, out);
}